// Round 1
// baseline (249.024 us; speedup 1.0000x reference)
//
#include <hip/hip_runtime.h>
#include <math.h>

#define B 64
#define N 4096
#define D 128
#define E 512
#define CHUNKS 16
#define ROWS_PER_BLOCK (N / CHUNKS)            // 256
#define WAVES 4
#define ROWS_PER_WAVE (ROWS_PER_BLOCK / WAVES) // 64
#define P (CHUNKS * WAVES)                     // 64 partials per batch
#define NEG_BIG -1e30f

// K0: proj_q[b,d] = dot(vecQuestions[b,:], Wq[d,:]) + bq[d]
// also emit wpq = proj_q * Wa[d] (score weight) so K1 needs no extra math.
__global__ __launch_bounds__(128) void proj_kernel(
    const float* __restrict__ vq, const float* __restrict__ Wq,
    const float* __restrict__ bq, const float* __restrict__ Wa,
    float* __restrict__ PQ, float* __restrict__ WPQ)
{
    int b = blockIdx.x, d = threadIdx.x;
    __shared__ float sv[E];
    for (int i = d; i < E; i += 128) sv[i] = vq[b * E + i];
    __syncthreads();
    const float4* wrow = (const float4*)(Wq + (size_t)d * E);
    const float4* vrow = (const float4*)sv;
    float s = 0.f;
    #pragma unroll 4
    for (int e4 = 0; e4 < E / 4; ++e4) {
        float4 w = wrow[e4];
        float4 v = vrow[e4];
        s += w.x * v.x + w.y * v.y + w.z * v.z + w.w * v.w;
    }
    float pq = s + bq[d];
    PQ[b * D + d] = pq;
    WPQ[b * D + d] = pq * Wa[d];
}

// K1: per (batch, chunk) block; each wave online-softmaxes 64 rows.
// Per row n: raw = (kb.pq*Wa)/max(||kb*pq||,eps) + ba; mask n>=cnt -> -1e30.
// Online update of (m, l, acc[128]) with kb row still in registers (kb read once).
__global__ __launch_bounds__(256) void att_partial_kernel(
    const float* __restrict__ kb, const int* __restrict__ cnt,
    const float* __restrict__ PQ, const float* __restrict__ WPQ,
    const float* __restrict__ ba,
    float* __restrict__ Mout, float* __restrict__ Lout, float* __restrict__ ACC)
{
    int blk = blockIdx.x;
    int b = blk / CHUNKS, c = blk % CHUNKS;
    int wave = threadIdx.x >> 6, lane = threadIdx.x & 63;
    int d0 = lane * 2;

    float2 pq  = *(const float2*)(PQ  + b * D + d0);
    float2 wpq = *(const float2*)(WPQ + b * D + d0);
    float bav = ba[0];
    int limit = cnt[b];

    float m = -INFINITY, l = 0.f;
    float2 acc = {0.f, 0.f};

    const float* base = kb + (size_t)b * N * D + d0;
    int n0 = c * ROWS_PER_BLOCK + wave;

    for (int i = 0; i < ROWS_PER_WAVE; ++i) {
        int n = n0 + i * WAVES;
        float2 kv = *(const float2*)(base + (size_t)n * D);

        float t1 = kv.x * wpq.x + kv.y * wpq.y;   // kb*pq*Wa contribution
        float ax = kv.x * pq.x, ay = kv.y * pq.y; // kb*pq
        float t2 = ax * ax + ay * ay;             // squared-norm contribution
        #pragma unroll
        for (int off = 32; off; off >>= 1) {
            t1 += __shfl_xor(t1, off, 64);
            t2 += __shfl_xor(t2, off, 64);
        }
        float raw = t1 / fmaxf(sqrtf(t2), 1e-12f) + bav;
        raw = (n >= limit) ? NEG_BIG : raw;       // exactly -1e30 like reference

        float mn = fmaxf(m, raw);
        float scale = __expf(m - mn);             // m=-inf first iter -> 0
        float p = __expf(raw - mn);
        l = l * scale + p;
        acc.x = acc.x * scale + p * kv.x;
        acc.y = acc.y * scale + p * kv.y;
        m = mn;
    }

    int pid = b * P + c * WAVES + wave;
    if (lane == 0) { Mout[pid] = m; Lout[pid] = l; }
    *(float2*)(ACC + (size_t)pid * D + d0) = acc;
}

// K2: merge P partials per batch: m* = max m_i; out = sum(e^{m_i-m*} acc_i) / sum(e^{m_i-m*} l_i)
__global__ __launch_bounds__(128) void merge_kernel(
    const float* __restrict__ Mv, const float* __restrict__ Lv,
    const float* __restrict__ ACC, float* __restrict__ out)
{
    int b = blockIdx.x, d = threadIdx.x;
    const float* Mb = Mv + b * P;
    const float* Lb = Lv + b * P;
    float mstar = -INFINITY;
    #pragma unroll 8
    for (int i = 0; i < P; ++i) mstar = fmaxf(mstar, Mb[i]);
    float lsum = 0.f, num = 0.f;
    for (int i = 0; i < P; ++i) {
        float cf = __expf(Mb[i] - mstar);
        lsum += cf * Lb[i];
        num  += cf * ACC[((size_t)b * P + i) * D + d];
    }
    out[b * D + d] = num / lsum;
}

extern "C" void kernel_launch(void* const* d_in, const int* in_sizes, int n_in,
                              void* d_out, int out_size, void* d_ws, size_t ws_size,
                              hipStream_t stream) {
    const float* kb  = (const float*)d_in[0];
    const float* vq  = (const float*)d_in[1];
    const int*   cnt = (const int*)d_in[2];
    const float* Wq  = (const float*)d_in[3];
    const float* bq  = (const float*)d_in[4];
    const float* Wa  = (const float*)d_in[5];
    const float* ba  = (const float*)d_in[6];
    float* out = (float*)d_out;

    float* ws = (float*)d_ws;
    float* PQ  = ws;                  // B*D
    float* WPQ = PQ + B * D;          // B*D
    float* M   = WPQ + B * D;         // B*P
    float* L   = M + B * P;           // B*P
    float* ACC = L + B * P;           // B*P*D

    proj_kernel<<<B, 128, 0, stream>>>(vq, Wq, bq, Wa, PQ, WPQ);
    att_partial_kernel<<<B * CHUNKS, 256, 0, stream>>>(kb, cnt, PQ, WPQ, ba, M, L, ACC);
    merge_kernel<<<B, 128, 0, stream>>>(M, L, ACC, out);
}

// Round 2
// 217.173 us; speedup vs baseline: 1.1467x; 1.1467x over previous
//
#include <hip/hip_runtime.h>
#include <math.h>

#define B 64
#define N 4096
#define D 128
#define E 512
#define CHUNKS 16
#define ROWS_PER_BLOCK (N / CHUNKS)            // 256
#define WAVES 4
#define ROWS_PER_WAVE (ROWS_PER_BLOCK / WAVES) // 64
#define TILE 16
#define TILES (ROWS_PER_WAVE / TILE)           // 4
#define P (CHUNKS * WAVES)                     // 64 partials per batch
#define NEG_BIG -1e30f
#define RSTRIDE 34                             // float2 pairs per LDS row (32 + 2 pad, keeps 16B align)

// Explicit wave-synchronous LDS fence: drain DS pipe + compiler memory barrier.
#define LDS_FENCE() asm volatile("s_waitcnt lgkmcnt(0)" ::: "memory")

// K0: proj_q[b,d] = dot(vecQuestions[b,:], Wq[d,:]) + bq[d]; WPQ = proj_q * Wa.
// grid (B, 2) x 128 threads; 2 threads per d, each a 256-wide half-dot.
__global__ __launch_bounds__(128) void proj_kernel(
    const float* __restrict__ vq, const float* __restrict__ Wq,
    const float* __restrict__ bq, const float* __restrict__ Wa,
    float* __restrict__ PQ, float* __restrict__ WPQ)
{
    int b = blockIdx.x;
    int d = blockIdx.y * 64 + (threadIdx.x >> 1);
    int eh = threadIdx.x & 1;
    const float4* w = (const float4*)(Wq + (size_t)d * E + eh * (E / 2));
    const float4* v = (const float4*)(vq + (size_t)b * E + eh * (E / 2));
    float s = 0.f;
    #pragma unroll 8
    for (int i = 0; i < E / 8; ++i) {
        float4 a = w[i], x = v[i];
        s += a.x * x.x + a.y * x.y + a.z * x.z + a.w * x.w;
    }
    s += __shfl_xor(s, 1);
    if (eh == 0) {
        float pq = s + bq[d];
        PQ[b * D + d] = pq;
        WPQ[b * D + d] = pq * Wa[d];
    }
}

// K1: per (batch, chunk) block; each wave online-softmaxes 64 rows in 16-row tiles.
__global__ __launch_bounds__(256) void att_partial_kernel(
    const float* __restrict__ kb, const int* __restrict__ cnt,
    const float* __restrict__ PQ, const float* __restrict__ WPQ,
    const float* __restrict__ ba,
    float* __restrict__ Mout, float* __restrict__ Lout, float* __restrict__ ACC)
{
    __shared__ float2 sP[WAVES][TILE * RSTRIDE];

    int blk = blockIdx.x;
    int b = blk / CHUNKS, c = blk % CHUNKS;
    int wave = threadIdx.x >> 6, lane = threadIdx.x & 63;
    int half = lane >> 5;          // which row of the 2-row load group
    int l5 = lane & 31;            // d-quad index (d = l5*4 .. l5*4+3)
    int rq_r = lane >> 2;          // phase-B: row this lane reduces (0..15)
    int rq_q = lane & 3;           // phase-B: quarter of the row

    float4 pq  = *(const float4*)(PQ  + b * D + l5 * 4);
    float4 wpq = *(const float4*)(WPQ + b * D + l5 * 4);
    float bav = ba[0];
    int limit = cnt[b];

    float m = -INFINITY, l = 0.f;
    float4 acc = {0.f, 0.f, 0.f, 0.f};

    int nwave = c * ROWS_PER_BLOCK + wave * ROWS_PER_WAVE;   // wave's first row
    const float* lbase = kb + (size_t)b * N * D + (size_t)nwave * D + half * D + l5 * 4;

    // preload tile 0 (8 x float4 = rows 2j+half, d-quad l5)
    float4 kv[8];
    #pragma unroll
    for (int j = 0; j < 8; ++j)
        kv[j] = *(const float4*)(lbase + (size_t)(2 * j) * D);

    #pragma unroll
    for (int t = 0; t < TILES; ++t) {
        // ---- phase A: per-lane partials -> LDS ----
        #pragma unroll
        for (int j = 0; j < 8; ++j) {
            float4 k4 = kv[j];
            float s1 = k4.x * wpq.x + k4.y * wpq.y + k4.z * wpq.z + k4.w * wpq.w;
            float ax = k4.x * pq.x, ay = k4.y * pq.y, az = k4.z * pq.z, aw = k4.w * pq.w;
            float s2 = ax * ax + ay * ay + az * az + aw * aw;
            sP[wave][(2 * j + half) * RSTRIDE + l5] = make_float2(s1, s2);
        }

        // issue next tile's loads BEFORE the fence so they overlap phase B
        float4 kvn[8];
        if (t + 1 < TILES) {
            #pragma unroll
            for (int j = 0; j < 8; ++j)
                kvn[j] = *(const float4*)(lbase + (size_t)((t + 1) * TILE + 2 * j) * D);
        }

        LDS_FENCE();   // writes visible to all lanes of this wave

        // ---- phase B: transpose-read, reduce, online softmax ----
        const float2* rowp = &sP[wave][rq_r * RSTRIDE + rq_q * 8];
        float4 a0 = ((const float4*)rowp)[0];
        float4 a1 = ((const float4*)rowp)[1];
        float4 a2 = ((const float4*)rowp)[2];
        float4 a3 = ((const float4*)rowp)[3];
        float t1 = ((a0.x + a0.z) + (a1.x + a1.z)) + ((a2.x + a2.z) + (a3.x + a3.z));
        float t2 = ((a0.y + a0.w) + (a1.y + a1.w)) + ((a2.y + a2.w) + (a3.y + a3.w));
        t1 += __shfl_xor(t1, 1); t2 += __shfl_xor(t2, 1);
        t1 += __shfl_xor(t1, 2); t2 += __shfl_xor(t2, 2);
        // all 4 q-lanes of row rq_r now hold full (t1,t2)

        int n = nwave + t * TILE + rq_r;
        float raw = t1 / fmaxf(sqrtf(t2), 1e-12f) + bav;
        raw = (n >= limit) ? NEG_BIG : raw;   // exactly -1e30 like reference

        float mt = raw;
        mt = fmaxf(mt, __shfl_xor(mt, 4));
        mt = fmaxf(mt, __shfl_xor(mt, 8));
        mt = fmaxf(mt, __shfl_xor(mt, 16));
        mt = fmaxf(mt, __shfl_xor(mt, 32));
        float mnew = fmaxf(m, mt);
        float scale = __expf(m - mnew);       // m=-inf first tile -> 0
        float p = __expf(raw - mnew);

        float ps = p;
        ps += __shfl_xor(ps, 4);
        ps += __shfl_xor(ps, 8);
        ps += __shfl_xor(ps, 16);
        ps += __shfl_xor(ps, 32);
        l = l * scale + ps;
        m = mnew;

        acc.x *= scale; acc.y *= scale; acc.z *= scale; acc.w *= scale;
        #pragma unroll
        for (int j = 0; j < 8; ++j) {
            float pj = __shfl(p, 8 * j + 4 * half);  // p of row 2j+half (q=0 copy)
            acc.x += pj * kv[j].x; acc.y += pj * kv[j].y;
            acc.z += pj * kv[j].z; acc.w += pj * kv[j].w;
        }

        #pragma unroll
        for (int j = 0; j < 8; ++j) kv[j] = kvn[j];
    }

    // combine the two half-row sets (each half accumulated its 8 rows/tile)
    acc.x += __shfl_xor(acc.x, 32);
    acc.y += __shfl_xor(acc.y, 32);
    acc.z += __shfl_xor(acc.z, 32);
    acc.w += __shfl_xor(acc.w, 32);

    int pid = b * P + c * WAVES + wave;
    if (lane == 0) { Mout[pid] = m; Lout[pid] = l; }
    if (half == 0)
        *(float4*)(ACC + (size_t)pid * D + l5 * 4) = acc;
}

// K2: merge P=64 partials per batch. One wave per batch; cf via shuffles.
__global__ __launch_bounds__(64) void merge_kernel(
    const float* __restrict__ Mv, const float* __restrict__ Lv,
    const float* __restrict__ ACC, float* __restrict__ out)
{
    int b = blockIdx.x, lane = threadIdx.x;
    float mi = Mv[b * P + lane];
    float li = Lv[b * P + lane];
    float mstar = mi;
    #pragma unroll
    for (int off = 32; off; off >>= 1) mstar = fmaxf(mstar, __shfl_xor(mstar, off));
    float cf = __expf(mi - mstar);
    float ls = cf * li;
    #pragma unroll
    for (int off = 32; off; off >>= 1) ls += __shfl_xor(ls, off);

    float2 num = {0.f, 0.f};
    const float2* accb = (const float2*)(ACC + (size_t)b * P * D);
    #pragma unroll 4
    for (int i = 0; i < P; ++i) {
        float cfi = __shfl(cf, i);
        float2 av = accb[(size_t)i * (D / 2) + lane];
        num.x += cfi * av.x;
        num.y += cfi * av.y;
    }
    float inv = 1.f / ls;
    *(float2*)(out + b * D + lane * 2) = make_float2(num.x * inv, num.y * inv);
}

extern "C" void kernel_launch(void* const* d_in, const int* in_sizes, int n_in,
                              void* d_out, int out_size, void* d_ws, size_t ws_size,
                              hipStream_t stream) {
    const float* kb  = (const float*)d_in[0];
    const float* vq  = (const float*)d_in[1];
    const int*   cnt = (const int*)d_in[2];
    const float* Wq  = (const float*)d_in[3];
    const float* bq  = (const float*)d_in[4];
    const float* Wa  = (const float*)d_in[5];
    const float* ba  = (const float*)d_in[6];
    float* out = (float*)d_out;

    float* ws = (float*)d_ws;
    float* PQ  = ws;                  // B*D
    float* WPQ = PQ + B * D;          // B*D
    float* M   = WPQ + B * D;         // B*P
    float* L   = M + B * P;           // B*P
    float* ACC = L + B * P;           // B*P*D

    proj_kernel<<<dim3(B, 2), 128, 0, stream>>>(vq, Wq, bq, Wa, PQ, WPQ);
    att_partial_kernel<<<B * CHUNKS, 256, 0, stream>>>(kb, cnt, PQ, WPQ, ba, M, L, ACC);
    merge_kernel<<<B, 64, 0, stream>>>(M, L, ACC, out);
}

// Round 3
// 216.218 us; speedup vs baseline: 1.1517x; 1.0044x over previous
//
#include <hip/hip_runtime.h>
#include <math.h>

#define B 64
#define N 4096
#define D 128
#define E 512
#define CHUNKS 16
#define ROWS_PER_BLOCK (N / CHUNKS)            // 256
#define WAVES 4
#define ROWS_PER_WAVE (ROWS_PER_BLOCK / WAVES) // 64
#define TILE 16
#define TILES (ROWS_PER_WAVE / TILE)           // 4
#define P (CHUNKS * WAVES)                     // 64 partials per batch
#define NEG_BIG -1e30f
#define RSTRIDE 34                             // float2 per LDS row (32 + 2 pad, 16B-aligned)

// Explicit wave-synchronous LDS fence: drain DS pipe + compiler memory barrier.
#define LDS_FENCE() asm volatile("s_waitcnt lgkmcnt(0)" ::: "memory")

// K0: proj_q[b,d] = dot(vecQuestions[b,:], Wq[d,:]) + bq[d]; WPQ = proj_q * Wa.
__global__ __launch_bounds__(128) void proj_kernel(
    const float* __restrict__ vq, const float* __restrict__ Wq,
    const float* __restrict__ bq, const float* __restrict__ Wa,
    float* __restrict__ PQ, float* __restrict__ WPQ)
{
    int b = blockIdx.x;
    int d = blockIdx.y * 64 + (threadIdx.x >> 1);
    int eh = threadIdx.x & 1;
    const float4* w = (const float4*)(Wq + (size_t)d * E + eh * (E / 2));
    const float4* v = (const float4*)(vq + (size_t)b * E + eh * (E / 2));
    float s = 0.f;
    #pragma unroll 8
    for (int i = 0; i < E / 8; ++i) {
        float4 a = w[i], x = v[i];
        s += a.x * x.x + a.y * x.y + a.z * x.z + a.w * x.w;
    }
    s += __shfl_xor(s, 1);
    if (eh == 0) {
        float pq = s + bq[d];
        PQ[b * D + d] = pq;
        WPQ[b * D + d] = pq * Wa[d];
    }
}

// K1: fixed-shift softmax partials. raw is bounded (|raw-ba| <= ||Wa||2 ~ 1.3
// after L2-normalize), so exp(raw - (ba+2)) never overflows; masked rows
// (-1e30) underflow to exactly 0. No online max, no rescale, pure-add merge.
__global__ __launch_bounds__(256) void att_partial_kernel(
    const float* __restrict__ kb, const int* __restrict__ cnt,
    const float* __restrict__ PQ, const float* __restrict__ WPQ,
    const float* __restrict__ ba,
    float* __restrict__ Lout, float* __restrict__ ACC)
{
    __shared__ float2 sP[WAVES][TILE * RSTRIDE];

    int blk = blockIdx.x;
    int b = blk / CHUNKS, c = blk % CHUNKS;
    int wave = threadIdx.x >> 6, lane = threadIdx.x & 63;
    int half = lane >> 5;          // which row of each 2-row load group
    int l5 = lane & 31;            // d-quad index (d = l5*4 .. l5*4+3)
    int rq_r = lane >> 2;          // phase-B: row this lane reduces (0..15)
    int rq_q = lane & 3;           // phase-B: quarter of the row

    float4 pq  = *(const float4*)(PQ  + b * D + l5 * 4);
    float4 wpq = *(const float4*)(WPQ + b * D + l5 * 4);
    float bav = ba[0];
    int limit = cnt[b];
    float K = bav + 2.0f;          // fixed softmax shift, batch-uniform

    float l = 0.f;
    float4 acc = {0.f, 0.f, 0.f, 0.f};

    int nwave = c * ROWS_PER_BLOCK + wave * ROWS_PER_WAVE;
    const float* lbase = kb + (size_t)b * N * D + (size_t)nwave * D + half * D + l5 * 4;

    float4 kv[8];
    #pragma unroll
    for (int j = 0; j < 8; ++j)
        kv[j] = *(const float4*)(lbase + (size_t)(2 * j) * D);

    #pragma unroll
    for (int t = 0; t < TILES; ++t) {
        // ---- phase A: per-lane partial (s1 = kb.(pq*Wa), s2 = ||kb*pq||^2 part) ----
        #pragma unroll
        for (int j = 0; j < 8; ++j) {
            float4 k4 = kv[j];
            float s1 = k4.x * wpq.x + k4.y * wpq.y + k4.z * wpq.z + k4.w * wpq.w;
            float ax = k4.x * pq.x, ay = k4.y * pq.y, az = k4.z * pq.z, aw = k4.w * pq.w;
            float s2 = ax * ax + ay * ay + az * az + aw * aw;
            sP[wave][(2 * j + half) * RSTRIDE + l5] = make_float2(s1, s2);
        }

        // issue next tile's loads BEFORE the fence so they overlap phase B
        float4 kvn[8];
        if (t + 1 < TILES) {
            #pragma unroll
            for (int j = 0; j < 8; ++j)
                kvn[j] = *(const float4*)(lbase + (size_t)((t + 1) * TILE + 2 * j) * D);
        }

        LDS_FENCE();

        // ---- phase B: transpose-read, reduce, fixed-shift exp ----
        const float2* rowp = &sP[wave][rq_r * RSTRIDE + rq_q * 8];
        float4 a0 = ((const float4*)rowp)[0];
        float4 a1 = ((const float4*)rowp)[1];
        float4 a2 = ((const float4*)rowp)[2];
        float4 a3 = ((const float4*)rowp)[3];
        float t1 = ((a0.x + a0.z) + (a1.x + a1.z)) + ((a2.x + a2.z) + (a3.x + a3.z));
        float t2 = ((a0.y + a0.w) + (a1.y + a1.w)) + ((a2.y + a2.w) + (a3.y + a3.w));
        t1 += __shfl_xor(t1, 1); t2 += __shfl_xor(t2, 1);
        t1 += __shfl_xor(t1, 2); t2 += __shfl_xor(t2, 2);

        int n = nwave + t * TILE + rq_r;
        float inv = __builtin_amdgcn_rsqf(fmaxf(t2, 1e-24f));  // 1/max(||.||,1e-12)
        float raw = t1 * inv + bav;
        raw = (n >= limit) ? NEG_BIG : raw;   // exp underflows to exact 0
        if (limit == 0) raw = K;              // all-masked: uniform softmax
        float p = __expf(raw - K);

        l += p;   // per-lane; reduced once at kernel end

        #pragma unroll
        for (int j = 0; j < 8; ++j) {
            float pj = __shfl(p, 8 * j + 4 * half);  // p of row 2j+half
            acc.x += pj * kv[j].x; acc.y += pj * kv[j].y;
            acc.z += pj * kv[j].z; acc.w += pj * kv[j].w;
        }

        #pragma unroll
        for (int j = 0; j < 8; ++j) kv[j] = kvn[j];
    }

    // l: each row's p lives (identically) in 4 lanes; summing over the 16
    // lanes sharing rq_q (xor 4,8,16,32) yields exact sum over this wave's rows.
    l += __shfl_xor(l, 4);
    l += __shfl_xor(l, 8);
    l += __shfl_xor(l, 16);
    l += __shfl_xor(l, 32);

    // combine the two half-row accumulator sets
    acc.x += __shfl_xor(acc.x, 32);
    acc.y += __shfl_xor(acc.y, 32);
    acc.z += __shfl_xor(acc.z, 32);
    acc.w += __shfl_xor(acc.w, 32);

    int pid = b * P + c * WAVES + wave;
    if (lane == 0) Lout[pid] = l;
    if (half == 0)
        *(float4*)(ACC + (size_t)pid * D + l5 * 4) = acc;
}

// K2: pure-add merge (all partials share the same shift K).
__global__ __launch_bounds__(128) void merge_kernel(
    const float* __restrict__ Lv, const float* __restrict__ ACC,
    float* __restrict__ out)
{
    int b = blockIdx.x, d = threadIdx.x;
    const float* Lb = Lv + b * P;
    float lsum = 0.f;
    #pragma unroll 8
    for (int i = 0; i < P; ++i) lsum += Lb[i];     // uniform -> scalar loads
    float num = 0.f;
    const float* accb = ACC + (size_t)b * P * D + d;
    #pragma unroll 8
    for (int i = 0; i < P; ++i) num += accb[(size_t)i * D];
    out[b * D + d] = num / lsum;
}

extern "C" void kernel_launch(void* const* d_in, const int* in_sizes, int n_in,
                              void* d_out, int out_size, void* d_ws, size_t ws_size,
                              hipStream_t stream) {
    const float* kb  = (const float*)d_in[0];
    const float* vq  = (const float*)d_in[1];
    const int*   cnt = (const int*)d_in[2];
    const float* Wq  = (const float*)d_in[3];
    const float* bq  = (const float*)d_in[4];
    const float* Wa  = (const float*)d_in[5];
    const float* ba  = (const float*)d_in[6];
    float* out = (float*)d_out;

    float* ws = (float*)d_ws;
    float* PQ  = ws;                  // B*D
    float* WPQ = PQ + B * D;          // B*D
    float* L   = WPQ + B * D;         // B*P
    float* ACC = L + B * P;           // B*P*D

    proj_kernel<<<dim3(B, 2), 128, 0, stream>>>(vq, Wq, bq, Wa, PQ, WPQ);
    att_partial_kernel<<<B * CHUNKS, 256, 0, stream>>>(kb, cnt, PQ, WPQ, ba, L, ACC);
    merge_kernel<<<B, 128, 0, stream>>>(L, ACC, out);
}

// Round 4
// 205.321 us; speedup vs baseline: 1.2129x; 1.0531x over previous
//
#include <hip/hip_runtime.h>
#include <math.h>

#define B 64
#define N 4096
#define D 128
#define E 512
#define CHUNKS 32
#define ROWS_PER_BLOCK (N / CHUNKS)            // 128
#define WAVES 4
#define ROWS_PER_WAVE (ROWS_PER_BLOCK / WAVES) // 32
#define TILE 16
#define MAXTILES (ROWS_PER_WAVE / TILE)        // 2
#define P (CHUNKS * WAVES)                     // 128 partials per batch
#define NEG_BIG -1e30f
#define RSTRIDE 34                             // float2 per LDS row (32 + 2 pad)

// Wave-synchronous LDS fence: drain DS pipe + compiler memory barrier.
#define LDS_FENCE() asm volatile("s_waitcnt lgkmcnt(0)" ::: "memory")

// K0: proj_q[b,d] = dot(vecQuestions[b,:], Wq[d,:]) + bq[d]; WPQ = proj_q * Wa.
__global__ __launch_bounds__(128) void proj_kernel(
    const float* __restrict__ vq, const float* __restrict__ Wq,
    const float* __restrict__ bq, const float* __restrict__ Wa,
    float* __restrict__ PQ, float* __restrict__ WPQ)
{
    int b = blockIdx.x;
    int d = blockIdx.y * 64 + (threadIdx.x >> 1);
    int eh = threadIdx.x & 1;
    const float4* w = (const float4*)(Wq + (size_t)d * E + eh * (E / 2));
    const float4* v = (const float4*)(vq + (size_t)b * E + eh * (E / 2));
    float s = 0.f;
    #pragma unroll 8
    for (int i = 0; i < E / 8; ++i) {
        float4 a = w[i], x = v[i];
        s += a.x * x.x + a.y * x.y + a.z * x.z + a.w * x.w;
    }
    s += __shfl_xor(s, 1);
    if (eh == 0) {
        float pq = s + bq[d];
        PQ[b * D + d] = pq;
        WPQ[b * D + d] = pq * Wa[d];
    }
}

// K1: fixed-shift softmax partials, masked-row load skipping.
// Rows n >= limit have p == 0 exactly -> never load them. cnt==0 means
// uniform softmax over ALL rows (eff=N, p=1 everywhere).
__global__ __launch_bounds__(256) void att_partial_kernel(
    const float* __restrict__ kb, const int* __restrict__ cnt,
    const float* __restrict__ PQ, const float* __restrict__ WPQ,
    const float* __restrict__ ba,
    float* __restrict__ Lout, float* __restrict__ ACC)
{
    __shared__ float2 sP[WAVES][TILE * RSTRIDE];

    int blk = blockIdx.x;
    int b = blk >> 5, c = blk & (CHUNKS - 1);
    int wave = threadIdx.x >> 6, lane = threadIdx.x & 63;
    int half = lane >> 5;          // which row of each 2-row load group
    int l5 = lane & 31;            // d-quad index (d = l5*4 .. l5*4+3)
    int rq_r = lane >> 2;          // phase-B: row this lane reduces (0..15)
    int rq_q = lane & 3;           // phase-B: quarter of the row

    int limit = cnt[b];
    int eff = (limit == 0) ? N : limit;    // cnt==0 -> need all rows (uniform)
    int nwave = c * ROWS_PER_BLOCK + wave * ROWS_PER_WAVE;
    int pid = b * P + c * WAVES + wave;

    int wact = eff - nwave;                // active rows in this wave's range
    if (wact <= 0) {
        // fully masked: partials must be zero (ws is poisoned each launch)
        if (lane == 0) Lout[pid] = 0.f;
        if (half == 0)
            *(float4*)(ACC + (size_t)pid * D + l5 * 4) = make_float4(0.f, 0.f, 0.f, 0.f);
        return;
    }
    int ntiles = (wact + TILE - 1) >> 4;
    if (ntiles > MAXTILES) ntiles = MAXTILES;

    float4 pq  = *(const float4*)(PQ  + b * D + l5 * 4);
    float4 wpq = *(const float4*)(WPQ + b * D + l5 * 4);
    float bav = ba[0];
    float K = bav + 2.0f;          // fixed softmax shift (|raw-ba| <= ||Wa|| ~1.3)

    float l = 0.f;
    float4 acc = {0.f, 0.f, 0.f, 0.f};

    const float* lbase = kb + (size_t)b * N * D + (size_t)nwave * D + half * D + l5 * 4;

    float4 kv[8];
    #pragma unroll
    for (int j = 0; j < 8; ++j)
        kv[j] = *(const float4*)(lbase + (size_t)(2 * j) * D);

    for (int t = 0; t < ntiles; ++t) {
        // ---- phase A: per-lane partials -> LDS ----
        #pragma unroll
        for (int j = 0; j < 8; ++j) {
            float4 k4 = kv[j];
            float s1 = k4.x * wpq.x + k4.y * wpq.y + k4.z * wpq.z + k4.w * wpq.w;
            float ax = k4.x * pq.x, ay = k4.y * pq.y, az = k4.z * pq.z, aw = k4.w * pq.w;
            float s2 = ax * ax + ay * ay + az * az + aw * aw;
            sP[wave][(2 * j + half) * RSTRIDE + l5] = make_float2(s1, s2);
        }

        // issue next tile's loads BEFORE the fence so they overlap phase B
        float4 kvn[8];
        if (t + 1 < ntiles) {
            #pragma unroll
            for (int j = 0; j < 8; ++j)
                kvn[j] = *(const float4*)(lbase + (size_t)((t + 1) * TILE + 2 * j) * D);
        }

        LDS_FENCE();

        // ---- phase B: transpose-read, reduce, fixed-shift exp ----
        const float2* rowp = &sP[wave][rq_r * RSTRIDE + rq_q * 8];
        float4 a0 = ((const float4*)rowp)[0];
        float4 a1 = ((const float4*)rowp)[1];
        float4 a2 = ((const float4*)rowp)[2];
        float4 a3 = ((const float4*)rowp)[3];
        float t1 = ((a0.x + a0.z) + (a1.x + a1.z)) + ((a2.x + a2.z) + (a3.x + a3.z));
        float t2 = ((a0.y + a0.w) + (a1.y + a1.w)) + ((a2.y + a2.w) + (a3.y + a3.w));
        t1 += __shfl_xor(t1, 1); t2 += __shfl_xor(t2, 1);
        t1 += __shfl_xor(t1, 2); t2 += __shfl_xor(t2, 2);

        int n = nwave + t * TILE + rq_r;
        float inv = __builtin_amdgcn_rsqf(fmaxf(t2, 1e-24f));  // 1/max(||.||,1e-12)
        float raw = t1 * inv + bav;
        raw = (n >= limit) ? NEG_BIG : raw;   // exp underflows to exact 0
        if (limit == 0) raw = K;              // all-masked: uniform softmax
        float p = __expf(raw - K);

        l += p;   // per-lane; reduced once at kernel end

        #pragma unroll
        for (int j = 0; j < 8; ++j) {
            float pj = __shfl(p, 8 * j + 4 * half);  // p of row 2j+half
            acc.x += pj * kv[j].x; acc.y += pj * kv[j].y;
            acc.z += pj * kv[j].z; acc.w += pj * kv[j].w;
        }

        #pragma unroll
        for (int j = 0; j < 8; ++j) kv[j] = kvn[j];
    }

    // each row's p lives identically in 4 lanes; sum over xor 4,8,16,32
    // gives the exact row-sum for this wave.
    l += __shfl_xor(l, 4);
    l += __shfl_xor(l, 8);
    l += __shfl_xor(l, 16);
    l += __shfl_xor(l, 32);

    // combine the two half-row accumulator sets
    acc.x += __shfl_xor(acc.x, 32);
    acc.y += __shfl_xor(acc.y, 32);
    acc.z += __shfl_xor(acc.z, 32);
    acc.w += __shfl_xor(acc.w, 32);

    if (lane == 0) Lout[pid] = l;
    if (half == 0)
        *(float4*)(ACC + (size_t)pid * D + l5 * 4) = acc;
}

// K2: pure-add merge (all partials share the same shift K).
__global__ __launch_bounds__(128) void merge_kernel(
    const float* __restrict__ Lv, const float* __restrict__ ACC,
    float* __restrict__ out)
{
    int b = blockIdx.x, d = threadIdx.x;
    const float* Lb = Lv + b * P;
    float lsum = 0.f;
    #pragma unroll 8
    for (int i = 0; i < P; ++i) lsum += Lb[i];     // uniform -> scalar loads
    float num = 0.f;
    const float* accb = ACC + (size_t)b * P * D + d;
    #pragma unroll 8
    for (int i = 0; i < P; ++i) num += accb[(size_t)i * D];
    out[b * D + d] = num / lsum;
}

extern "C" void kernel_launch(void* const* d_in, const int* in_sizes, int n_in,
                              void* d_out, int out_size, void* d_ws, size_t ws_size,
                              hipStream_t stream) {
    const float* kb  = (const float*)d_in[0];
    const float* vq  = (const float*)d_in[1];
    const int*   cnt = (const int*)d_in[2];
    const float* Wq  = (const float*)d_in[3];
    const float* bq  = (const float*)d_in[4];
    const float* Wa  = (const float*)d_in[5];
    const float* ba  = (const float*)d_in[6];
    float* out = (float*)d_out;

    float* ws = (float*)d_ws;
    float* PQ  = ws;                  // B*D
    float* WPQ = PQ + B * D;          // B*D
    float* L   = WPQ + B * D;         // B*P
    float* ACC = L + B * P;           // B*P*D

    proj_kernel<<<dim3(B, 2), 128, 0, stream>>>(vq, Wq, bq, Wa, PQ, WPQ);
    att_partial_kernel<<<B * CHUNKS, 256, 0, stream>>>(kb, cnt, PQ, WPQ, ba, L, ACC);
    merge_kernel<<<B, 128, 0, stream>>>(L, ACC, out);
}